// Round 2
// baseline (738.137 us; speedup 1.0000x reference)
//
#include <hip/hip_runtime.h>
#include <hip/hip_bf16.h>
#include <math.h>

#define N_NODES 100000
#define N_EDGES 1600000
#define FIN 14
#define H 64
#define NB 105
#define S_CNT 10000
#define SCAN_BLOCKS 391   // ceil(100000/256)
#define NBKT 391          // dst buckets of 256 nodes
#define BBLK 250          // blocks for edge binning
#define EPB 6400          // edges per bin block: 250*6400 = 1.6M exact

// ---------------- degree histogram (edges only; +1 self-loop added in dis) ----
__global__ __launch_bounds__(256) void deg_kernel(const int* __restrict__ dst,
                                                  int* __restrict__ deg) {
    int e = blockIdx.x * 256 + threadIdx.x;   // grid exact: 6250*256 = 1.6M
    atomicAdd(&deg[dst[e]], 1);
}

__global__ __launch_bounds__(256) void stem_kernel(const int* __restrict__ idx,
                                                   float* __restrict__ stem01) {
    int i = blockIdx.x * 256 + threadIdx.x;
    if (i < S_CNT) stem01[idx[i]] = 1.0f;
}

__global__ __launch_bounds__(256) void dis_kernel(const int* __restrict__ deg,
                                                  float* __restrict__ dis) {
    int i = blockIdx.x * 256 + threadIdx.x;
    if (i < N_NODES) dis[i] = rsqrtf((float)deg[i] + 1.0f);  // +1 self loop
}

// ---------------- rowptr: scan deg ----------------
__global__ __launch_bounds__(256) void scan1_kernel(const int* __restrict__ deg,
                                                    int* __restrict__ rowptr,
                                                    int* __restrict__ bsum) {
    __shared__ int s[256];
    int t = threadIdx.x;
    int i = blockIdx.x * 256 + t;
    int v = (i < N_NODES) ? deg[i] : 0;
    s[t] = v;
    __syncthreads();
#pragma unroll
    for (int o = 1; o < 256; o <<= 1) {
        int x = (t >= o) ? s[t - o] : 0;
        __syncthreads();
        s[t] += x;
        __syncthreads();
    }
    if (i < N_NODES) rowptr[i + 1] = s[t];
    if (t == 255) bsum[blockIdx.x] = s[255];
}

__global__ __launch_bounds__(512) void scan2_kernel(const int* __restrict__ bsum,
                                                    int* __restrict__ boff) {
    __shared__ int s[512];
    int t = threadIdx.x;
    int v = (t < SCAN_BLOCKS) ? bsum[t] : 0;
    s[t] = v;
    __syncthreads();
#pragma unroll
    for (int o = 1; o < 512; o <<= 1) {
        int x = (t >= o) ? s[t - o] : 0;
        __syncthreads();
        s[t] += x;
        __syncthreads();
    }
    if (t < SCAN_BLOCKS) boff[t] = s[t] - v;   // exclusive
}

__global__ __launch_bounds__(256) void scan3_kernel(const int* __restrict__ boff,
                                                    int* __restrict__ rowptr) {
    int t = threadIdx.x;
    int i = blockIdx.x * 256 + t;
    if (i < N_NODES) rowptr[i + 1] += boff[blockIdx.x];
    if (i == 0) rowptr[0] = 0;
}

// ---------------- atomic-free binned CSR scatter ----------------
// A1: per-(block,bucket) histogram. hist layout: [bucket*BBLK + block]
__global__ __launch_bounds__(256) void bincnt_kernel(const int* __restrict__ dst,
                                                     int* __restrict__ hist) {
    __shared__ int lh[NBKT];
    int t = threadIdx.x;
    for (int i = t; i < NBKT; i += 256) lh[i] = 0;
    __syncthreads();
    int e0 = blockIdx.x * EPB;
    for (int i = t; i < EPB; i += 256) atomicAdd(&lh[dst[e0 + i] >> 8], 1);
    __syncthreads();
    for (int i = t; i < NBKT; i += 256) hist[i * BBLK + blockIdx.x] = lh[i];
}

// A2: per-bucket exclusive scan over blocks, + bucket base from rowptr (in place)
__global__ __launch_bounds__(256) void binscan_kernel(int* __restrict__ hist,
                                                      const int* __restrict__ rowptr) {
    __shared__ int s[256];
    int t = threadIdx.x, b = blockIdx.x;
    int v = (t < BBLK) ? hist[b * BBLK + t] : 0;
    s[t] = v;
    __syncthreads();
#pragma unroll
    for (int o = 1; o < 256; o <<= 1) {
        int x = (t >= o) ? s[t - o] : 0;
        __syncthreads();
        s[t] += x;
        __syncthreads();
    }
    if (t < BBLK) hist[b * BBLK + t] = rowptr[b * 256] + s[t] - v;  // excl + base
}

// A3: re-read edges, place packed (src | dstlow<<17) into contiguous
// per-(block,bucket) runs -> full-line writes, no global atomics.
__global__ __launch_bounds__(256) void binscat_kernel(const int* __restrict__ src,
                                                      const int* __restrict__ dst,
                                                      const int* __restrict__ hist,
                                                      int* __restrict__ tmp) {
    __shared__ int lofs[NBKT];
    __shared__ int lcnt[NBKT];
    int t = threadIdx.x;
    for (int i = t; i < NBKT; i += 256) {
        lofs[i] = hist[i * BBLK + blockIdx.x];
        lcnt[i] = 0;
    }
    __syncthreads();
    int e0 = blockIdx.x * EPB;
    for (int i = t; i < EPB; i += 256) {
        int s = src[e0 + i], d = dst[e0 + i];
        int b = d >> 8;
        int r = atomicAdd(&lcnt[b], 1);
        tmp[lofs[b] + r] = s | ((d & 255) << 17);   // src < 2^17, dstlow 8 bits
    }
}

// B: one block per bucket; LDS cursors; exact CSR scatter confined to the
// bucket's ~16 KB col window (single CU -> L2 write merging).
__global__ __launch_bounds__(256) void bsort_kernel(const int* __restrict__ tmp,
                                                    const int* __restrict__ rowptr,
                                                    int* __restrict__ col) {
    __shared__ int cur[256];
    int t = threadIdx.x, b = blockIdx.x;
    int n0 = b * 256;
    int idx = n0 + t;
    cur[t] = (idx < N_NODES) ? rowptr[idx] : 0;
    __syncthreads();
    int beg = rowptr[n0];
    int nend = n0 + 256; if (nend > N_NODES) nend = N_NODES;
    int end = rowptr[nend];
    for (int i = beg + t; i < end; i += 256) {
        int p = tmp[i];
        int pos = atomicAdd(&cur[p >> 17], 1);
        col[pos] = p & 0x1FFFF;
    }
}

// ---------------- pad+transpose W heads into WpT[224][64] --------------------
// WpT[c][k] = W[k][c'] ; c in [0,105) -> Wb, c in [112,217) -> Ws, else 0.
__global__ __launch_bounds__(256) void wpadT_kernel(const float* __restrict__ Wb,
                                                    const float* __restrict__ Ws,
                                                    float* __restrict__ WpT) {
    int i = blockIdx.x * 256 + threadIdx.x;
    if (i < 224 * 64) {
        int c = i >> 6, k = i & 63;
        float w = 0.f;
        if (c < NB) w = Wb[k * NB + c];
        else if (c >= 112 && c < 112 + NB) w = Ws[k * NB + (c - 112)];
        WpT[i] = w;
    }
}

// ---------------- xws1 = ([x, stem] @ W1) * dis  (K=15) ----------------
__global__ __launch_bounds__(256) void xw1_kernel(const float* __restrict__ x,
                                                  const float* __restrict__ stem01,
                                                  const float* __restrict__ dis,
                                                  const float* __restrict__ W1,
                                                  float* __restrict__ xws) {
    __shared__ __align__(16) float W1s[15 * 64];
    __shared__ __align__(16) float xs[4][16];
    int tid = threadIdx.x;
    for (int i = tid; i < 960; i += 256) W1s[i] = W1[i];
    int n0 = blockIdx.x * 4;                     // grid exact: 25000*4 = 100000
    if (tid < 60) {
        int r = tid / 15, k = tid % 15;
        int n = n0 + r;
        xs[r][k] = (k < FIN) ? x[n * FIN + k] : stem01[n];
    }
    __syncthreads();
    int r = tid >> 6, f = tid & 63;
    float acc = 0.f;
#pragma unroll
    for (int k = 0; k < 15; k++) acc += xs[r][k] * W1s[k * 64 + f];
    xws[(n0 + r) * 64 + f] = acc * dis[n0 + r];
}

// ---------------- CSR aggregation + fused epilogue ----------------
__global__ __launch_bounds__(256) void agg_csr_kernel(const float* __restrict__ xws,
                                                      const int* __restrict__ rowptr,
                                                      const int* __restrict__ col,
                                                      const float* __restrict__ dis,
                                                      const float* __restrict__ bias,
                                                      const float* __restrict__ drop,
                                                      float* __restrict__ hout) {
    int node = (blockIdx.x * 256 + threadIdx.x) >> 6;  // grid exact: 25000*4
    int f = threadIdx.x & 63;
    int beg = rowptr[node], end = rowptr[node + 1];
    float acc0 = xws[node * 64 + f];   // self loop (already * dis[node])
    float acc1 = 0.f, acc2 = 0.f, acc3 = 0.f;
    int j = beg;
    for (; j + 4 <= end; j += 4) {
        int s0 = col[j], s1 = col[j + 1], s2 = col[j + 2], s3 = col[j + 3];
        acc0 += xws[s0 * 64 + f];
        acc1 += xws[s1 * 64 + f];
        acc2 += xws[s2 * 64 + f];
        acc3 += xws[s3 * 64 + f];
    }
    for (; j < end; j++) acc0 += xws[col[j] * 64 + f];
    float acc = (acc0 + acc1) + (acc2 + acc3);
    float r = fmaxf(fmaf(dis[node], acc, bias[f]), 0.f) * drop[node * 64 + f];
    hout[node * 64 + f] = r;
}

// ---------------- xws2 = (h1 @ W2) * dis  (64x64), in-place safe -------------
__global__ __launch_bounds__(256) void xw2_kernel(const float* __restrict__ h,
                                                  const float* __restrict__ dis,
                                                  const float* __restrict__ W2,
                                                  float* __restrict__ xws) {
    __shared__ __align__(16) float W2s[64 * 64];     // 16 KB
    __shared__ __align__(16) float hsT[64 * 68];     // k-major, pad 68: 17 KB
    int tid = threadIdx.x;
    for (int i = tid; i < 4096; i += 256) W2s[i] = W2[i];
    int n0 = blockIdx.x * 64;                        // grid 1563, tail guarded
    for (int i = tid; i < 4096; i += 256) {
        int m = i >> 6, k = i & 63;
        int n = n0 + m;
        hsT[k * 68 + m] = (n < N_NODES) ? h[n * 64 + k] : 0.f;
    }
    __syncthreads();
    int fg = tid & 15, mg = tid >> 4;
    int f0 = fg * 4, m0 = mg * 4;
    float acc[4][4];
#pragma unroll
    for (int i = 0; i < 4; i++)
#pragma unroll
        for (int j = 0; j < 4; j++) acc[i][j] = 0.f;
    for (int k = 0; k < 64; k++) {
        float4 w = *(const float4*)&W2s[k * 64 + f0];
        float4 hv = *(const float4*)&hsT[k * 68 + m0];
        float hh[4] = {hv.x, hv.y, hv.z, hv.w};
#pragma unroll
        for (int i = 0; i < 4; i++) {
            acc[i][0] += hh[i] * w.x;
            acc[i][1] += hh[i] * w.y;
            acc[i][2] += hh[i] * w.z;
            acc[i][3] += hh[i] * w.w;
        }
    }
#pragma unroll
    for (int i = 0; i < 4; i++) {
        int n = n0 + m0 + i;
        if (n < N_NODES) {
            float ds = dis[n];
            float4 r = make_float4(acc[i][0] * ds, acc[i][1] * ds,
                                   acc[i][2] * ds, acc[i][3] * ds);
            *(float4*)&xws[n * 64 + f0] = r;
        }
    }
}

// ---------------- fused head: matmul + bias + gumbel softmax -----------------
// Wave owns 16 nodes; half-wave 0 = block head, half-wave 1 = stem head.
// Lane lp covers cols {lp, lp+32, lp+64, lp+96(guarded)} -> all global
// loads/stores 128B-contiguous per half-wave. h2 tile staged per-wave in LDS
// (wave-local, no barriers), read via uniform-address float4 broadcasts.
// W read from L2 as WpT[col][k] float4 over k, double-buffered.
__global__ __launch_bounds__(256) void fhead_kernel(const float* __restrict__ h2,
                                                    const float* __restrict__ WpT,
                                                    const float* __restrict__ bb,
                                                    const float* __restrict__ bs,
                                                    const float* __restrict__ gb,
                                                    const float* __restrict__ gs,
                                                    float* __restrict__ out) {
    __shared__ __align__(16) float hl[4][16 * 64];   // 16 KB
    const size_t NA = (size_t)N_NODES * NB;
    int tid = threadIdx.x;
    int widx = tid >> 6, lane = tid & 63;
    int wid = blockIdx.x * 4 + widx;
    int n0 = wid * 16;
    if (n0 >= N_NODES) return;                        // no barriers in kernel
    int half = lane >> 5;                             // 0: block, 1: stem
    int lp = lane & 31;

    // stage h2[n0..n0+15][:] -> hl[widx] (coalesced; wave-local, no barrier)
    {
        const float4* src = (const float4*)(h2 + (size_t)n0 * 64);
        float4* dstp = (float4*)hl[widx];
#pragma unroll
        for (int q = 0; q < 4; q++) dstp[q * 64 + lane] = src[q * 64 + lane];
    }

    int hoff = half * 112;
    const float* bias = half ? bs : bb;
    const float* g = half ? gs : gb;
    bool v3 = (lp + 96) < NB;                         // lp <= 8
    int c3 = v3 ? (lp + 96) : 104;                    // clamped (finite data)
    const float* w0p = WpT + (size_t)(hoff + lp) * 64;
    const float* w1p = WpT + (size_t)(hoff + lp + 32) * 64;
    const float* w2p = WpT + (size_t)(hoff + lp + 64) * 64;
    const float* w3p = WpT + (size_t)(hoff + c3) * 64;
    float bv0 = bias[lp], bv1 = bias[lp + 32], bv2 = bias[lp + 64];
    float bv3 = v3 ? bias[lp + 96] : 0.f;

    float acc[16][4];
#pragma unroll
    for (int j = 0; j < 16; j++)
#pragma unroll
        for (int r = 0; r < 4; r++) acc[j][r] = 0.f;

    const float* hw = hl[widx];
    // prime k-chunk 0
    float4 w0 = *(const float4*)&w0p[0];
    float4 w1 = *(const float4*)&w1p[0];
    float4 w2 = *(const float4*)&w2p[0];
    float4 w3 = *(const float4*)&w3p[0];
    for (int k4 = 0; k4 < 16; k4++) {
        int kn = (k4 < 15) ? (k4 + 1) * 4 : 60;       // prefetch next (clamped)
        float4 nw0 = *(const float4*)&w0p[kn];
        float4 nw1 = *(const float4*)&w1p[kn];
        float4 nw2 = *(const float4*)&w2p[kn];
        float4 nw3 = *(const float4*)&w3p[kn];
#pragma unroll
        for (int j = 0; j < 16; j++) {
            float4 hq = *(const float4*)&hw[j * 64 + k4 * 4];  // uniform bcast
            acc[j][0] += hq.x * w0.x + hq.y * w0.y + hq.z * w0.z + hq.w * w0.w;
            acc[j][1] += hq.x * w1.x + hq.y * w1.y + hq.z * w1.z + hq.w * w1.w;
            acc[j][2] += hq.x * w2.x + hq.y * w2.y + hq.z * w2.z + hq.w * w2.w;
            acc[j][3] += hq.x * w3.x + hq.y * w3.y + hq.z * w3.z + hq.w * w3.w;
        }
        w0 = nw0; w1 = nw1; w2 = nw2; w3 = nw3;
    }

    // epilogue: per node j: logits, half-wave softmax reduce, stores
#pragma unroll
    for (int j = 0; j < 16; j++) {
        int n = n0 + j;
        const float* gr = g + (size_t)n * NB;
        float l0 = acc[j][0] + bv0;
        float l1 = acc[j][1] + bv1;
        float l2 = acc[j][2] + bv2;
        float l3 = acc[j][3] + bv3;
        float z0 = l0 + gr[lp];
        float z1 = l1 + gr[lp + 32];
        float z2 = l2 + gr[lp + 64];
        float z3 = v3 ? (l3 + gr[lp + 96]) : -INFINITY;
        float m = fmaxf(fmaxf(z0, z1), fmaxf(z2, z3));
#pragma unroll
        for (int off = 16; off; off >>= 1) m = fmaxf(m, __shfl_xor(m, off));
        float e0 = __expf(z0 - m);
        float e1 = __expf(z1 - m);
        float e2 = __expf(z2 - m);
        float e3 = v3 ? __expf(z3 - m) : 0.f;
        float s = (e0 + e1) + (e2 + e3);
#pragma unroll
        for (int off = 16; off; off >>= 1) s += __shfl_xor(s, off);
        float inv = 1.f / s;
        float* lo = out + (size_t)half * NA + (size_t)n * NB;
        float* so = lo + 2 * NA;
        lo[lp] = l0; lo[lp + 32] = l1; lo[lp + 64] = l2;
        so[lp] = e0 * inv; so[lp + 32] = e1 * inv; so[lp + 64] = e2 * inv;
        if (v3) { lo[lp + 96] = l3; so[lp + 96] = e3 * inv; }
    }
}

extern "C" void kernel_launch(void* const* d_in, const int* in_sizes, int n_in,
                              void* d_out, int out_size, void* d_ws, size_t ws_size,
                              hipStream_t stream) {
    const float* x     = (const float*)d_in[0];
    const float* W1    = (const float*)d_in[1];
    const float* b1    = (const float*)d_in[2];
    const float* W2    = (const float*)d_in[3];
    const float* b2    = (const float*)d_in[4];
    const float* Wb    = (const float*)d_in[5];
    const float* bb    = (const float*)d_in[6];
    const float* Ws    = (const float*)d_in[7];
    const float* bs    = (const float*)d_in[8];
    const float* drop1 = (const float*)d_in[9];
    const float* drop2 = (const float*)d_in[10];
    const float* gb    = (const float*)d_in[11];
    const float* gs    = (const float*)d_in[12];
    const int* edge    = (const int*)d_in[13];   // [2, E]
    const int* stem    = (const int*)d_in[14];   // [S]
    float* out = (float*)d_out;

    // workspace (4-byte elems):
    // A[N*64] | B[N*64] | dis[N] | stem01[N] | deg[N] | rowptr[N+1] |
    // hist[N] (NBKT*BBLK=97750 used) | bsum | boff | col[E] | WpT[224*64]
    float* A      = (float*)d_ws;
    float* B      = A + (size_t)N_NODES * 64;
    float* dis    = B + (size_t)N_NODES * 64;
    float* stem01 = dis + N_NODES;
    int*   deg    = (int*)(stem01 + N_NODES);
    int*   rowptr = deg + N_NODES;
    int*   hist   = rowptr + (N_NODES + 1);
    int*   bsum   = hist + N_NODES;
    int*   boff   = bsum + SCAN_BLOCKS;
    int*   col    = boff + SCAN_BLOCKS;
    float* WpT    = (float*)(col + N_EDGES);
    int*   tmp    = (int*)d_out;   // 6.4 MB scratch; out fully overwritten later

    const int* esrc = edge;
    const int* edst = edge + N_EDGES;

    hipMemsetAsync(deg, 0, N_NODES * sizeof(int), stream);
    hipMemsetAsync(stem01, 0, N_NODES * sizeof(float), stream);

    deg_kernel<<<N_EDGES / 256, 256, 0, stream>>>(edst, deg);
    stem_kernel<<<(S_CNT + 255) / 256, 256, 0, stream>>>(stem, stem01);
    dis_kernel<<<SCAN_BLOCKS, 256, 0, stream>>>(deg, dis);
    wpadT_kernel<<<(224 * 64 + 255) / 256, 256, 0, stream>>>(Wb, Ws, WpT);

    // rowptr
    scan1_kernel<<<SCAN_BLOCKS, 256, 0, stream>>>(deg, rowptr, bsum);
    scan2_kernel<<<1, 512, 0, stream>>>(bsum, boff);
    scan3_kernel<<<SCAN_BLOCKS, 256, 0, stream>>>(boff, rowptr);

    // atomic-free binned CSR scatter
    bincnt_kernel<<<BBLK, 256, 0, stream>>>(edst, hist);
    binscan_kernel<<<NBKT, 256, 0, stream>>>(hist, rowptr);
    binscat_kernel<<<BBLK, 256, 0, stream>>>(esrc, edst, hist, tmp);
    bsort_kernel<<<NBKT, 256, 0, stream>>>(tmp, rowptr, col);

    // layer 1: xws1 -> A; h1 -> B
    xw1_kernel<<<N_NODES / 4, 256, 0, stream>>>(x, stem01, dis, W1, A);
    agg_csr_kernel<<<(N_NODES * 64) / 256, 256, 0, stream>>>(A, rowptr, col, dis, b1, drop1, B);

    // layer 2: xws2 -> B (in-place over h1); h2 -> A
    xw2_kernel<<<(N_NODES + 63) / 64, 256, 0, stream>>>(B, dis, W2, B);
    agg_csr_kernel<<<(N_NODES * 64) / 256, 256, 0, stream>>>(B, rowptr, col, dis, b2, drop2, A);

    // fused heads: logits + gumbel softmax -> all 4 output sections
    fhead_kernel<<<(N_NODES / 16 + 3) / 4, 256, 0, stream>>>(A, WpT, bb, bs, gb, gs, out);
}

// Round 3
// 729.374 us; speedup vs baseline: 1.0120x; 1.0120x over previous
//
#include <hip/hip_runtime.h>
#include <hip/hip_bf16.h>
#include <math.h>

#define N_NODES 100000
#define N_EDGES 1600000
#define FIN 14
#define H 64
#define NB 105
#define S_CNT 10000
#define SCAN_BLOCKS 391   // ceil(100000/256)
#define NBKT 391          // dst buckets of 256 nodes
#define BBLK 250          // blocks for edge binning
#define EPB 6400          // edges per bin block: 250*6400 = 1.6M exact

// ---------------- degree histogram (edges only; +1 self-loop added in dis) ----
__global__ __launch_bounds__(256) void deg_kernel(const int* __restrict__ dst,
                                                  int* __restrict__ deg) {
    int e = blockIdx.x * 256 + threadIdx.x;   // grid exact: 6250*256 = 1.6M
    atomicAdd(&deg[dst[e]], 1);
}

__global__ __launch_bounds__(256) void stem_kernel(const int* __restrict__ idx,
                                                   float* __restrict__ stem01) {
    int i = blockIdx.x * 256 + threadIdx.x;
    if (i < S_CNT) stem01[idx[i]] = 1.0f;
}

__global__ __launch_bounds__(256) void dis_kernel(const int* __restrict__ deg,
                                                  float* __restrict__ dis) {
    int i = blockIdx.x * 256 + threadIdx.x;
    if (i < N_NODES) dis[i] = rsqrtf((float)deg[i] + 1.0f);  // +1 self loop
}

// ---------------- rowptr: scan deg ----------------
__global__ __launch_bounds__(256) void scan1_kernel(const int* __restrict__ deg,
                                                    int* __restrict__ rowptr,
                                                    int* __restrict__ bsum) {
    __shared__ int s[256];
    int t = threadIdx.x;
    int i = blockIdx.x * 256 + t;
    int v = (i < N_NODES) ? deg[i] : 0;
    s[t] = v;
    __syncthreads();
#pragma unroll
    for (int o = 1; o < 256; o <<= 1) {
        int x = (t >= o) ? s[t - o] : 0;
        __syncthreads();
        s[t] += x;
        __syncthreads();
    }
    if (i < N_NODES) rowptr[i + 1] = s[t];
    if (t == 255) bsum[blockIdx.x] = s[255];
}

__global__ __launch_bounds__(512) void scan2_kernel(const int* __restrict__ bsum,
                                                    int* __restrict__ boff) {
    __shared__ int s[512];
    int t = threadIdx.x;
    int v = (t < SCAN_BLOCKS) ? bsum[t] : 0;
    s[t] = v;
    __syncthreads();
#pragma unroll
    for (int o = 1; o < 512; o <<= 1) {
        int x = (t >= o) ? s[t - o] : 0;
        __syncthreads();
        s[t] += x;
        __syncthreads();
    }
    if (t < SCAN_BLOCKS) boff[t] = s[t] - v;   // exclusive
}

__global__ __launch_bounds__(256) void scan3_kernel(const int* __restrict__ boff,
                                                    int* __restrict__ rowptr) {
    int t = threadIdx.x;
    int i = blockIdx.x * 256 + t;
    if (i < N_NODES) rowptr[i + 1] += boff[blockIdx.x];
    if (i == 0) rowptr[0] = 0;
}

// ---------------- atomic-free binned CSR scatter ----------------
// A1: per-(block,bucket) histogram. hist layout: [bucket*BBLK + block]
__global__ __launch_bounds__(256) void bincnt_kernel(const int* __restrict__ dst,
                                                     int* __restrict__ hist) {
    __shared__ int lh[NBKT];
    int t = threadIdx.x;
    for (int i = t; i < NBKT; i += 256) lh[i] = 0;
    __syncthreads();
    int e0 = blockIdx.x * EPB;
    for (int i = t; i < EPB; i += 256) atomicAdd(&lh[dst[e0 + i] >> 8], 1);
    __syncthreads();
    for (int i = t; i < NBKT; i += 256) hist[i * BBLK + blockIdx.x] = lh[i];
}

// A2: per-bucket exclusive scan over blocks, + bucket base from rowptr (in place)
__global__ __launch_bounds__(256) void binscan_kernel(int* __restrict__ hist,
                                                      const int* __restrict__ rowptr) {
    __shared__ int s[256];
    int t = threadIdx.x, b = blockIdx.x;
    int v = (t < BBLK) ? hist[b * BBLK + t] : 0;
    s[t] = v;
    __syncthreads();
#pragma unroll
    for (int o = 1; o < 256; o <<= 1) {
        int x = (t >= o) ? s[t - o] : 0;
        __syncthreads();
        s[t] += x;
        __syncthreads();
    }
    if (t < BBLK) hist[b * BBLK + t] = rowptr[b * 256] + s[t] - v;  // excl + base
}

// A3: re-read edges, place packed (src | dstlow<<17) into contiguous
// per-(block,bucket) runs -> full-line writes, no global atomics.
__global__ __launch_bounds__(256) void binscat_kernel(const int* __restrict__ src,
                                                      const int* __restrict__ dst,
                                                      const int* __restrict__ hist,
                                                      int* __restrict__ tmp) {
    __shared__ int lofs[NBKT];
    __shared__ int lcnt[NBKT];
    int t = threadIdx.x;
    for (int i = t; i < NBKT; i += 256) {
        lofs[i] = hist[i * BBLK + blockIdx.x];
        lcnt[i] = 0;
    }
    __syncthreads();
    int e0 = blockIdx.x * EPB;
    for (int i = t; i < EPB; i += 256) {
        int s = src[e0 + i], d = dst[e0 + i];
        int b = d >> 8;
        int r = atomicAdd(&lcnt[b], 1);
        tmp[lofs[b] + r] = s | ((d & 255) << 17);   // src < 2^17, dstlow 8 bits
    }
}

// B: one block per bucket; LDS cursors; exact CSR scatter confined to the
// bucket's ~16 KB col window (single CU -> L2 write merging).
__global__ __launch_bounds__(256) void bsort_kernel(const int* __restrict__ tmp,
                                                    const int* __restrict__ rowptr,
                                                    int* __restrict__ col) {
    __shared__ int cur[256];
    int t = threadIdx.x, b = blockIdx.x;
    int n0 = b * 256;
    int idx = n0 + t;
    cur[t] = (idx < N_NODES) ? rowptr[idx] : 0;
    __syncthreads();
    int beg = rowptr[n0];
    int nend = n0 + 256; if (nend > N_NODES) nend = N_NODES;
    int end = rowptr[nend];
    for (int i = beg + t; i < end; i += 256) {
        int p = tmp[i];
        int pos = atomicAdd(&cur[p >> 17], 1);
        col[pos] = p & 0x1FFFF;
    }
}

// ---------------- pad+transpose W heads into WpT[224][64] --------------------
// WpT[c][k] = W[k][c'] ; c in [0,105) -> Wb, c in [112,217) -> Ws, else 0.
__global__ __launch_bounds__(256) void wpadT_kernel(const float* __restrict__ Wb,
                                                    const float* __restrict__ Ws,
                                                    float* __restrict__ WpT) {
    int i = blockIdx.x * 256 + threadIdx.x;
    if (i < 224 * 64) {
        int c = i >> 6, k = i & 63;
        float w = 0.f;
        if (c < NB) w = Wb[k * NB + c];
        else if (c >= 112 && c < 112 + NB) w = Ws[k * NB + (c - 112)];
        WpT[i] = w;
    }
}

// ---------------- xws1 = ([x, stem] @ W1) * dis  (K=15) ----------------
__global__ __launch_bounds__(256) void xw1_kernel(const float* __restrict__ x,
                                                  const float* __restrict__ stem01,
                                                  const float* __restrict__ dis,
                                                  const float* __restrict__ W1,
                                                  float* __restrict__ xws) {
    __shared__ __align__(16) float W1s[15 * 64];
    __shared__ __align__(16) float xs[4][16];
    int tid = threadIdx.x;
    for (int i = tid; i < 960; i += 256) W1s[i] = W1[i];
    int n0 = blockIdx.x * 4;                     // grid exact: 25000*4 = 100000
    if (tid < 60) {
        int r = tid / 15, k = tid % 15;
        int n = n0 + r;
        xs[r][k] = (k < FIN) ? x[n * FIN + k] : stem01[n];
    }
    __syncthreads();
    int r = tid >> 6, f = tid & 63;
    float acc = 0.f;
#pragma unroll
    for (int k = 0; k < 15; k++) acc += xs[r][k] * W1s[k * 64 + f];
    xws[(n0 + r) * 64 + f] = acc * dis[n0 + r];
}

// ---------------- CSR aggregation + fused epilogue ----------------
__global__ __launch_bounds__(256) void agg_csr_kernel(const float* __restrict__ xws,
                                                      const int* __restrict__ rowptr,
                                                      const int* __restrict__ col,
                                                      const float* __restrict__ dis,
                                                      const float* __restrict__ bias,
                                                      const float* __restrict__ drop,
                                                      float* __restrict__ hout) {
    int node = (blockIdx.x * 256 + threadIdx.x) >> 6;  // grid exact: 25000*4
    int f = threadIdx.x & 63;
    int beg = rowptr[node], end = rowptr[node + 1];
    float acc0 = xws[node * 64 + f];   // self loop (already * dis[node])
    float acc1 = 0.f, acc2 = 0.f, acc3 = 0.f;
    int j = beg;
    for (; j + 4 <= end; j += 4) {
        int s0 = col[j], s1 = col[j + 1], s2 = col[j + 2], s3 = col[j + 3];
        acc0 += xws[s0 * 64 + f];
        acc1 += xws[s1 * 64 + f];
        acc2 += xws[s2 * 64 + f];
        acc3 += xws[s3 * 64 + f];
    }
    for (; j < end; j++) acc0 += xws[col[j] * 64 + f];
    float acc = (acc0 + acc1) + (acc2 + acc3);
    float r = fmaxf(fmaf(dis[node], acc, bias[f]), 0.f) * drop[node * 64 + f];
    hout[node * 64 + f] = r;
}

// ---------------- xws2 = (h1 @ W2) * dis  (64x64), in-place safe -------------
__global__ __launch_bounds__(256) void xw2_kernel(const float* __restrict__ h,
                                                  const float* __restrict__ dis,
                                                  const float* __restrict__ W2,
                                                  float* __restrict__ xws) {
    __shared__ __align__(16) float W2s[64 * 64];     // 16 KB
    __shared__ __align__(16) float hsT[64 * 68];     // k-major, pad 68: 17 KB
    int tid = threadIdx.x;
    for (int i = tid; i < 4096; i += 256) W2s[i] = W2[i];
    int n0 = blockIdx.x * 64;                        // grid 1563, tail guarded
    for (int i = tid; i < 4096; i += 256) {
        int m = i >> 6, k = i & 63;
        int n = n0 + m;
        hsT[k * 68 + m] = (n < N_NODES) ? h[n * 64 + k] : 0.f;
    }
    __syncthreads();
    int fg = tid & 15, mg = tid >> 4;
    int f0 = fg * 4, m0 = mg * 4;
    float acc[4][4];
#pragma unroll
    for (int i = 0; i < 4; i++)
#pragma unroll
        for (int j = 0; j < 4; j++) acc[i][j] = 0.f;
    for (int k = 0; k < 64; k++) {
        float4 w = *(const float4*)&W2s[k * 64 + f0];
        float4 hv = *(const float4*)&hsT[k * 68 + m0];
        float hh[4] = {hv.x, hv.y, hv.z, hv.w};
#pragma unroll
        for (int i = 0; i < 4; i++) {
            acc[i][0] += hh[i] * w.x;
            acc[i][1] += hh[i] * w.y;
            acc[i][2] += hh[i] * w.z;
            acc[i][3] += hh[i] * w.w;
        }
    }
#pragma unroll
    for (int i = 0; i < 4; i++) {
        int n = n0 + m0 + i;
        if (n < N_NODES) {
            float ds = dis[n];
            float4 r = make_float4(acc[i][0] * ds, acc[i][1] * ds,
                                   acc[i][2] * ds, acc[i][3] * ds);
            *(float4*)&xws[n * 64 + f0] = r;
        }
    }
}

// ---------------- head logits: matmul + bias -> out sections 0,1 -------------
// Wave owns 8 nodes; half-wave 0 = block head, half-wave 1 = stem head.
// Lane lp covers cols {lp, lp+32, lp+64, lp+96(guarded)} -> all stores are
// 128B-contiguous per half-wave. h2 tile staged per-wave in LDS (wave-local,
// no barriers), read via uniform-address float4 broadcasts. W from L2
// (WpT[col][k], 56 KB resident). Low VGPR -> high occupancy, short waves.
__global__ __launch_bounds__(256) void hlog_kernel(const float* __restrict__ h2,
                                                   const float* __restrict__ WpT,
                                                   const float* __restrict__ bb,
                                                   const float* __restrict__ bs,
                                                   float* __restrict__ out) {
    __shared__ __align__(16) float hl[4][8 * 64];    // 8 KB/block
    const size_t NA = (size_t)N_NODES * NB;
    int tid = threadIdx.x;
    int widx = tid >> 6, lane = tid & 63;
    int wid = blockIdx.x * 4 + widx;
    int n0 = wid * 8;                                // grid exact: 12500 waves
    int half = lane >> 5;                            // 0: block, 1: stem
    int lp = lane & 31;

    // stage h2[n0..n0+7][:] -> hl[widx] (coalesced; wave-local, no barrier)
    {
        const float4* src = (const float4*)(h2 + (size_t)n0 * 64);
        float4* dstp = (float4*)hl[widx];
        dstp[lane] = src[lane];
        dstp[64 + lane] = src[64 + lane];
    }

    int hoff = half * 112;
    const float* bias = half ? bs : bb;
    bool v3 = (lp + 96) < NB;                        // lp <= 8
    int c3 = v3 ? (lp + 96) : 104;                   // clamped (finite data)
    const float* w0p = WpT + (size_t)(hoff + lp) * 64;
    const float* w1p = WpT + (size_t)(hoff + lp + 32) * 64;
    const float* w2p = WpT + (size_t)(hoff + lp + 64) * 64;
    const float* w3p = WpT + (size_t)(hoff + c3) * 64;
    float bv0 = bias[lp], bv1 = bias[lp + 32], bv2 = bias[lp + 64];
    float bv3 = v3 ? bias[lp + 96] : 0.f;

    float acc[8][4];
#pragma unroll
    for (int j = 0; j < 8; j++)
#pragma unroll
        for (int r = 0; r < 4; r++) acc[j][r] = 0.f;

    const float* hw = hl[widx];
#pragma unroll 4
    for (int k4 = 0; k4 < 16; k4++) {
        float4 w0 = *(const float4*)&w0p[k4 * 4];
        float4 w1 = *(const float4*)&w1p[k4 * 4];
        float4 w2 = *(const float4*)&w2p[k4 * 4];
        float4 w3 = *(const float4*)&w3p[k4 * 4];
#pragma unroll
        for (int j = 0; j < 8; j++) {
            float4 hq = *(const float4*)&hw[j * 64 + k4 * 4];  // uniform bcast
            acc[j][0] += hq.x * w0.x + hq.y * w0.y + hq.z * w0.z + hq.w * w0.w;
            acc[j][1] += hq.x * w1.x + hq.y * w1.y + hq.z * w1.z + hq.w * w1.w;
            acc[j][2] += hq.x * w2.x + hq.y * w2.y + hq.z * w2.z + hq.w * w2.w;
            acc[j][3] += hq.x * w3.x + hq.y * w3.y + hq.z * w3.z + hq.w * w3.w;
        }
    }

    // stores: per node, 3 full + 1 guarded segment per half-wave (128B each)
    float* ob = out + (size_t)half * NA + (size_t)n0 * NB;
#pragma unroll
    for (int j = 0; j < 8; j++) {
        float* lo = ob + (size_t)j * NB;
        lo[lp] = acc[j][0] + bv0;
        lo[lp + 32] = acc[j][1] + bv1;
        lo[lp + 64] = acc[j][2] + bv2;
        if (v3) lo[lp + 96] = acc[j][3] + bv3;
    }
}

// ---------------- gumbel softmax: wave per (node, head) row ------------------
__global__ __launch_bounds__(256) void gsm_kernel(const float* __restrict__ gb,
                                                  const float* __restrict__ gs,
                                                  float* __restrict__ out) {
    const size_t NA = (size_t)N_NODES * NB;
    int wid = blockIdx.x * 4 + (threadIdx.x >> 6);
    int lane = threadIdx.x & 63;
    int n = wid >> 1;
    if (n >= N_NODES) return;
    int head = wid & 1;
    const float* L = out + (head ? NA : 0) + (size_t)n * NB;
    const float* g = (head ? gs : gb) + (size_t)n * NB;
    float z0 = L[lane] + g[lane];
    float z1 = (lane < NB - 64) ? L[lane + 64] + g[lane + 64] : -INFINITY;
    float m = fmaxf(z0, z1);
#pragma unroll
    for (int off = 32; off; off >>= 1) m = fmaxf(m, __shfl_xor(m, off));
    float e0 = __expf(z0 - m);
    float e1 = (lane < NB - 64) ? __expf(z1 - m) : 0.f;
    float s = e0 + e1;
#pragma unroll
    for (int off = 32; off; off >>= 1) s += __shfl_xor(s, off);
    float inv = 1.f / s;
    float* o = out + (2 + head) * NA + (size_t)n * NB;
    o[lane] = e0 * inv;
    if (lane < NB - 64) o[lane + 64] = e1 * inv;
}

extern "C" void kernel_launch(void* const* d_in, const int* in_sizes, int n_in,
                              void* d_out, int out_size, void* d_ws, size_t ws_size,
                              hipStream_t stream) {
    const float* x     = (const float*)d_in[0];
    const float* W1    = (const float*)d_in[1];
    const float* b1    = (const float*)d_in[2];
    const float* W2    = (const float*)d_in[3];
    const float* b2    = (const float*)d_in[4];
    const float* Wb    = (const float*)d_in[5];
    const float* bb    = (const float*)d_in[6];
    const float* Ws    = (const float*)d_in[7];
    const float* bs    = (const float*)d_in[8];
    const float* drop1 = (const float*)d_in[9];
    const float* drop2 = (const float*)d_in[10];
    const float* gb    = (const float*)d_in[11];
    const float* gs    = (const float*)d_in[12];
    const int* edge    = (const int*)d_in[13];   // [2, E]
    const int* stem    = (const int*)d_in[14];   // [S]
    float* out = (float*)d_out;

    // workspace (4-byte elems):
    // A[N*64] | B[N*64] | dis[N] | stem01[N] | deg[N] | rowptr[N+1] |
    // hist[N] (NBKT*BBLK=97750 used) | bsum | boff | col[E] | WpT[224*64]
    float* A      = (float*)d_ws;
    float* B      = A + (size_t)N_NODES * 64;
    float* dis    = B + (size_t)N_NODES * 64;
    float* stem01 = dis + N_NODES;
    int*   deg    = (int*)(stem01 + N_NODES);
    int*   rowptr = deg + N_NODES;
    int*   hist   = rowptr + (N_NODES + 1);
    int*   bsum   = hist + N_NODES;
    int*   boff   = bsum + SCAN_BLOCKS;
    int*   col    = boff + SCAN_BLOCKS;
    float* WpT    = (float*)(col + N_EDGES);
    int*   tmp    = (int*)d_out;   // 6.4 MB scratch; out fully overwritten later

    const int* esrc = edge;
    const int* edst = edge + N_EDGES;

    hipMemsetAsync(deg, 0, N_NODES * sizeof(int), stream);
    hipMemsetAsync(stem01, 0, N_NODES * sizeof(float), stream);

    deg_kernel<<<N_EDGES / 256, 256, 0, stream>>>(edst, deg);
    stem_kernel<<<(S_CNT + 255) / 256, 256, 0, stream>>>(stem, stem01);
    dis_kernel<<<SCAN_BLOCKS, 256, 0, stream>>>(deg, dis);
    wpadT_kernel<<<(224 * 64 + 255) / 256, 256, 0, stream>>>(Wb, Ws, WpT);

    // rowptr
    scan1_kernel<<<SCAN_BLOCKS, 256, 0, stream>>>(deg, rowptr, bsum);
    scan2_kernel<<<1, 512, 0, stream>>>(bsum, boff);
    scan3_kernel<<<SCAN_BLOCKS, 256, 0, stream>>>(boff, rowptr);

    // atomic-free binned CSR scatter
    bincnt_kernel<<<BBLK, 256, 0, stream>>>(edst, hist);
    binscan_kernel<<<NBKT, 256, 0, stream>>>(hist, rowptr);
    binscat_kernel<<<BBLK, 256, 0, stream>>>(esrc, edst, hist, tmp);
    bsort_kernel<<<NBKT, 256, 0, stream>>>(tmp, rowptr, col);

    // layer 1: xws1 -> A; h1 -> B
    xw1_kernel<<<N_NODES / 4, 256, 0, stream>>>(x, stem01, dis, W1, A);
    agg_csr_kernel<<<(N_NODES * 64) / 256, 256, 0, stream>>>(A, rowptr, col, dis, b1, drop1, B);

    // layer 2: xws2 -> B (in-place over h1); h2 -> A
    xw2_kernel<<<(N_NODES + 63) / 64, 256, 0, stream>>>(B, dis, W2, B);
    agg_csr_kernel<<<(N_NODES * 64) / 256, 256, 0, stream>>>(B, rowptr, col, dis, b2, drop2, A);

    // heads: logits (sections 0,1) then gumbel softmax (sections 2,3)
    hlog_kernel<<<N_NODES / 8 / 4, 256, 0, stream>>>(A, WpT, bb, bs, out);
    gsm_kernel<<<(2 * N_NODES) / 4, 256, 0, stream>>>(gb, gs, out);
}

// Round 4
// 711.038 us; speedup vs baseline: 1.0381x; 1.0258x over previous
//
#include <hip/hip_runtime.h>
#include <hip/hip_bf16.h>
#include <math.h>

#define N_NODES 100000
#define N_EDGES 1600000
#define FIN 14
#define H 64
#define NB 105
#define S_CNT 10000
#define SCAN_BLOCKS 391   // ceil(100000/256)
#define NBKT 391          // dst buckets of 256 nodes
#define BBLK 250          // blocks for edge binning
#define EPB 6400          // edges per bin block: 250*6400 = 1.6M exact

// ---------------- degree histogram (edges only; +1 self-loop added in dis) ----
__global__ __launch_bounds__(256) void deg_kernel(const int* __restrict__ dst,
                                                  int* __restrict__ deg) {
    int e = blockIdx.x * 256 + threadIdx.x;   // grid exact: 6250*256 = 1.6M
    atomicAdd(&deg[dst[e]], 1);
}

__global__ __launch_bounds__(256) void stem_kernel(const int* __restrict__ idx,
                                                   float* __restrict__ stem01) {
    int i = blockIdx.x * 256 + threadIdx.x;
    if (i < S_CNT) stem01[idx[i]] = 1.0f;
}

__global__ __launch_bounds__(256) void dis_kernel(const int* __restrict__ deg,
                                                  float* __restrict__ dis) {
    int i = blockIdx.x * 256 + threadIdx.x;
    if (i < N_NODES) dis[i] = rsqrtf((float)deg[i] + 1.0f);  // +1 self loop
}

// ---------------- rowptr: scan deg ----------------
__global__ __launch_bounds__(256) void scan1_kernel(const int* __restrict__ deg,
                                                    int* __restrict__ rowptr,
                                                    int* __restrict__ bsum) {
    __shared__ int s[256];
    int t = threadIdx.x;
    int i = blockIdx.x * 256 + t;
    int v = (i < N_NODES) ? deg[i] : 0;
    s[t] = v;
    __syncthreads();
#pragma unroll
    for (int o = 1; o < 256; o <<= 1) {
        int x = (t >= o) ? s[t - o] : 0;
        __syncthreads();
        s[t] += x;
        __syncthreads();
    }
    if (i < N_NODES) rowptr[i + 1] = s[t];
    if (t == 255) bsum[blockIdx.x] = s[255];
}

__global__ __launch_bounds__(512) void scan2_kernel(const int* __restrict__ bsum,
                                                    int* __restrict__ boff) {
    __shared__ int s[512];
    int t = threadIdx.x;
    int v = (t < SCAN_BLOCKS) ? bsum[t] : 0;
    s[t] = v;
    __syncthreads();
#pragma unroll
    for (int o = 1; o < 512; o <<= 1) {
        int x = (t >= o) ? s[t - o] : 0;
        __syncthreads();
        s[t] += x;
        __syncthreads();
    }
    if (t < SCAN_BLOCKS) boff[t] = s[t] - v;   // exclusive
}

__global__ __launch_bounds__(256) void scan3_kernel(const int* __restrict__ boff,
                                                    int* __restrict__ rowptr) {
    int t = threadIdx.x;
    int i = blockIdx.x * 256 + t;
    if (i < N_NODES) rowptr[i + 1] += boff[blockIdx.x];
    if (i == 0) rowptr[0] = 0;
}

// ---------------- atomic-free binned CSR scatter ----------------
// A1: per-(block,bucket) histogram. hist layout: [bucket*BBLK + block]
__global__ __launch_bounds__(256) void bincnt_kernel(const int* __restrict__ dst,
                                                     int* __restrict__ hist) {
    __shared__ int lh[NBKT];
    int t = threadIdx.x;
    for (int i = t; i < NBKT; i += 256) lh[i] = 0;
    __syncthreads();
    int e0 = blockIdx.x * EPB;
    for (int i = t; i < EPB; i += 256) atomicAdd(&lh[dst[e0 + i] >> 8], 1);
    __syncthreads();
    for (int i = t; i < NBKT; i += 256) hist[i * BBLK + blockIdx.x] = lh[i];
}

// A2: per-bucket exclusive scan over blocks, + bucket base from rowptr (in place)
__global__ __launch_bounds__(256) void binscan_kernel(int* __restrict__ hist,
                                                      const int* __restrict__ rowptr) {
    __shared__ int s[256];
    int t = threadIdx.x, b = blockIdx.x;
    int v = (t < BBLK) ? hist[b * BBLK + t] : 0;
    s[t] = v;
    __syncthreads();
#pragma unroll
    for (int o = 1; o < 256; o <<= 1) {
        int x = (t >= o) ? s[t - o] : 0;
        __syncthreads();
        s[t] += x;
        __syncthreads();
    }
    if (t < BBLK) hist[b * BBLK + t] = rowptr[b * 256] + s[t] - v;  // excl + base
}

// A3: re-read edges, place packed (src | dstlow<<17) into contiguous
// per-(block,bucket) runs -> full-line writes, no global atomics.
__global__ __launch_bounds__(256) void binscat_kernel(const int* __restrict__ src,
                                                      const int* __restrict__ dst,
                                                      const int* __restrict__ hist,
                                                      int* __restrict__ tmp) {
    __shared__ int lofs[NBKT];
    __shared__ int lcnt[NBKT];
    int t = threadIdx.x;
    for (int i = t; i < NBKT; i += 256) {
        lofs[i] = hist[i * BBLK + blockIdx.x];
        lcnt[i] = 0;
    }
    __syncthreads();
    int e0 = blockIdx.x * EPB;
    for (int i = t; i < EPB; i += 256) {
        int s = src[e0 + i], d = dst[e0 + i];
        int b = d >> 8;
        int r = atomicAdd(&lcnt[b], 1);
        tmp[lofs[b] + r] = s | ((d & 255) << 17);   // src < 2^17, dstlow 8 bits
    }
}

// B: one block per bucket; LDS cursors; exact CSR scatter confined to the
// bucket's ~16 KB col window (single CU -> L2 write merging).
__global__ __launch_bounds__(256) void bsort_kernel(const int* __restrict__ tmp,
                                                    const int* __restrict__ rowptr,
                                                    int* __restrict__ col) {
    __shared__ int cur[256];
    int t = threadIdx.x, b = blockIdx.x;
    int n0 = b * 256;
    int idx = n0 + t;
    cur[t] = (idx < N_NODES) ? rowptr[idx] : 0;
    __syncthreads();
    int beg = rowptr[n0];
    int nend = n0 + 256; if (nend > N_NODES) nend = N_NODES;
    int end = rowptr[nend];
    for (int i = beg + t; i < end; i += 256) {
        int p = tmp[i];
        int pos = atomicAdd(&cur[p >> 17], 1);
        col[pos] = p & 0x1FFFF;
    }
}

// ---------------- pad+transpose W heads into WpT[224][64] --------------------
// WpT[c][k] = W[k][c'] ; c in [0,105) -> Wb, c in [112,217) -> Ws, else 0.
__global__ __launch_bounds__(256) void wpadT_kernel(const float* __restrict__ Wb,
                                                    const float* __restrict__ Ws,
                                                    float* __restrict__ WpT) {
    int i = blockIdx.x * 256 + threadIdx.x;
    if (i < 224 * 64) {
        int c = i >> 6, k = i & 63;
        float w = 0.f;
        if (c < NB) w = Wb[k * NB + c];
        else if (c >= 112 && c < 112 + NB) w = Ws[k * NB + (c - 112)];
        WpT[i] = w;
    }
}

// ---------------- xws1 = ([x, stem] @ W1) * dis  (K=15) ----------------
__global__ __launch_bounds__(256) void xw1_kernel(const float* __restrict__ x,
                                                  const float* __restrict__ stem01,
                                                  const float* __restrict__ dis,
                                                  const float* __restrict__ W1,
                                                  float* __restrict__ xws) {
    __shared__ __align__(16) float W1s[15 * 64];
    __shared__ __align__(16) float xs[4][16];
    int tid = threadIdx.x;
    for (int i = tid; i < 960; i += 256) W1s[i] = W1[i];
    int n0 = blockIdx.x * 4;                     // grid exact: 25000*4 = 100000
    if (tid < 60) {
        int r = tid / 15, k = tid % 15;
        int n = n0 + r;
        xs[r][k] = (k < FIN) ? x[n * FIN + k] : stem01[n];
    }
    __syncthreads();
    int r = tid >> 6, f = tid & 63;
    float acc = 0.f;
#pragma unroll
    for (int k = 0; k < 15; k++) acc += xs[r][k] * W1s[k * 64 + f];
    xws[(n0 + r) * 64 + f] = acc * dis[n0 + r];
}

// ---------------- CSR aggregation + fused epilogue ----------------
__global__ __launch_bounds__(256) void agg_csr_kernel(const float* __restrict__ xws,
                                                      const int* __restrict__ rowptr,
                                                      const int* __restrict__ col,
                                                      const float* __restrict__ dis,
                                                      const float* __restrict__ bias,
                                                      const float* __restrict__ drop,
                                                      float* __restrict__ hout) {
    int node = (blockIdx.x * 256 + threadIdx.x) >> 6;  // grid exact: 25000*4
    int f = threadIdx.x & 63;
    int beg = rowptr[node], end = rowptr[node + 1];
    float acc0 = xws[node * 64 + f];   // self loop (already * dis[node])
    float acc1 = 0.f, acc2 = 0.f, acc3 = 0.f;
    int j = beg;
    for (; j + 4 <= end; j += 4) {
        int s0 = col[j], s1 = col[j + 1], s2 = col[j + 2], s3 = col[j + 3];
        acc0 += xws[s0 * 64 + f];
        acc1 += xws[s1 * 64 + f];
        acc2 += xws[s2 * 64 + f];
        acc3 += xws[s3 * 64 + f];
    }
    for (; j < end; j++) acc0 += xws[col[j] * 64 + f];
    float acc = (acc0 + acc1) + (acc2 + acc3);
    float r = fmaxf(fmaf(dis[node], acc, bias[f]), 0.f) * drop[node * 64 + f];
    hout[node * 64 + f] = r;
}

// ---------------- xws2 = (h1 @ W2) * dis  (64x64), in-place safe -------------
__global__ __launch_bounds__(256) void xw2_kernel(const float* __restrict__ h,
                                                  const float* __restrict__ dis,
                                                  const float* __restrict__ W2,
                                                  float* __restrict__ xws) {
    __shared__ __align__(16) float W2s[64 * 64];     // 16 KB
    __shared__ __align__(16) float hsT[64 * 68];     // k-major, pad 68: 17 KB
    int tid = threadIdx.x;
    for (int i = tid; i < 4096; i += 256) W2s[i] = W2[i];
    int n0 = blockIdx.x * 64;                        // grid 1563, tail guarded
    for (int i = tid; i < 4096; i += 256) {
        int m = i >> 6, k = i & 63;
        int n = n0 + m;
        hsT[k * 68 + m] = (n < N_NODES) ? h[n * 64 + k] : 0.f;
    }
    __syncthreads();
    int fg = tid & 15, mg = tid >> 4;
    int f0 = fg * 4, m0 = mg * 4;
    float acc[4][4];
#pragma unroll
    for (int i = 0; i < 4; i++)
#pragma unroll
        for (int j = 0; j < 4; j++) acc[i][j] = 0.f;
    for (int k = 0; k < 64; k++) {
        float4 w = *(const float4*)&W2s[k * 64 + f0];
        float4 hv = *(const float4*)&hsT[k * 68 + m0];
        float hh[4] = {hv.x, hv.y, hv.z, hv.w};
#pragma unroll
        for (int i = 0; i < 4; i++) {
            acc[i][0] += hh[i] * w.x;
            acc[i][1] += hh[i] * w.y;
            acc[i][2] += hh[i] * w.z;
            acc[i][3] += hh[i] * w.w;
        }
    }
#pragma unroll
    for (int i = 0; i < 4; i++) {
        int n = n0 + m0 + i;
        if (n < N_NODES) {
            float ds = dis[n];
            float4 r = make_float4(acc[i][0] * ds, acc[i][1] * ds,
                                   acc[i][2] * ds, acc[i][3] * ds);
            *(float4*)&xws[n * 64 + f0] = r;
        }
    }
}

// ---------------- fused head v3: LDS-W + matmul + gumbel softmax -------------
// blockIdx.y = head (0: block, 1: stem). W panel (112 cols x 64 k) staged in
// LDS, col-major with XOR-16 chunk swizzle -> wave64 ds_read_b128 across 64
// distinct cols is perfectly bank-balanced (8 accesses/bank = structural
// floor). Wave owns 8 nodes; lane owns cols {lane, lane+64}. All global
// accesses (h2, gumbel, logits, probs) are contiguous per wave. acc[8][2] =
// 16 VGPR -> high occupancy. One barrier (W staging); h staging wave-local.
__global__ __launch_bounds__(256) void fh2_kernel(const float* __restrict__ h2,
                                                  const float* __restrict__ WpT,
                                                  const float* __restrict__ bb,
                                                  const float* __restrict__ bs,
                                                  const float* __restrict__ gb,
                                                  const float* __restrict__ gs,
                                                  float* __restrict__ out) {
    __shared__ __align__(16) float Wl[112 * 64];     // 28672 B, swizzled
    __shared__ __align__(16) float hl[4][8 * 64];    // 8192 B
    const size_t NA = (size_t)N_NODES * NB;
    int tid = threadIdx.x;
    int head = blockIdx.y;

    // stage W panel: read coalesced, write swizzled
    // Wl slot: col*64 + ((chunk ^ (col&15))<<2) holds W[4*chunk..+3][col]
    {
        const float4* wsrc = (const float4*)(WpT + (size_t)head * 112 * 64);
        for (int i = tid; i < 112 * 16; i += 256) {
            int c = i >> 4, ch = i & 15;
            float4 v = wsrc[i];
            *(float4*)&Wl[(c << 6) + ((ch ^ (c & 15)) << 2)] = v;
        }
    }

    int widx = tid >> 6, lane = tid & 63;
    int n0 = (blockIdx.x * 4 + widx) * 8;            // grid exact: 3125*4*8

    // stage h2[n0..n0+7][:] -> hl[widx] (coalesced; wave-local)
    {
        const float4* src = (const float4*)(h2 + (size_t)n0 * 64);
        float4* dstp = (float4*)hl[widx];
        dstp[lane] = src[lane];
        dstp[64 + lane] = src[64 + lane];
    }
    __syncthreads();

    float acc[8][2];
#pragma unroll
    for (int j = 0; j < 8; j++) { acc[j][0] = 0.f; acc[j][1] = 0.f; }

    const float* hw = hl[widx];
    int sw = lane & 15;
    int b0 = lane << 6;                              // col = lane
    int b1 = (lane + 64) << 6;                       // col = lane+64 (0-pad >=105)
#pragma unroll 4
    for (int k4 = 0; k4 < 16; k4++) {
        int wo = (k4 ^ sw) << 2;
        float4 w0 = *(const float4*)&Wl[b0 + wo];
        float4 w1 = *(const float4*)&Wl[b1 + wo];
#pragma unroll
        for (int j = 0; j < 8; j++) {
            float4 hq = *(const float4*)&hw[(j << 6) + (k4 << 2)];  // broadcast
            acc[j][0] += hq.x * w0.x + hq.y * w0.y + hq.z * w0.z + hq.w * w0.w;
            acc[j][1] += hq.x * w1.x + hq.y * w1.y + hq.z * w1.z + hq.w * w1.w;
        }
    }

    // epilogue: bias + gumbel + full-wave softmax; all accesses contiguous
    bool v1 = lane < (NB - 64);                      // lane < 41
    const float* bias = head ? bs : bb;
    const float* g = head ? gs : gb;
    float bv0 = bias[lane];
    float bv1 = v1 ? bias[lane + 64] : 0.f;
    float* obase = out + (size_t)head * NA;
#pragma unroll
    for (int j = 0; j < 8; j++) {
        int n = n0 + j;
        const float* gr = g + (size_t)n * NB;
        float l0 = acc[j][0] + bv0;
        float l1 = acc[j][1] + bv1;
        float z0 = l0 + gr[lane];
        float z1 = v1 ? (l1 + gr[lane + 64]) : -INFINITY;
        float m = fmaxf(z0, z1);
#pragma unroll
        for (int off = 32; off; off >>= 1) m = fmaxf(m, __shfl_xor(m, off));
        float e0 = __expf(z0 - m);
        float e1 = v1 ? __expf(z1 - m) : 0.f;
        float s = e0 + e1;
#pragma unroll
        for (int off = 32; off; off >>= 1) s += __shfl_xor(s, off);
        float inv = 1.f / s;
        float* lo = obase + (size_t)n * NB;
        float* so = lo + 2 * NA;
        lo[lane] = l0;
        so[lane] = e0 * inv;
        if (v1) { lo[lane + 64] = l1; so[lane + 64] = e1 * inv; }
    }
}

extern "C" void kernel_launch(void* const* d_in, const int* in_sizes, int n_in,
                              void* d_out, int out_size, void* d_ws, size_t ws_size,
                              hipStream_t stream) {
    const float* x     = (const float*)d_in[0];
    const float* W1    = (const float*)d_in[1];
    const float* b1    = (const float*)d_in[2];
    const float* W2    = (const float*)d_in[3];
    const float* b2    = (const float*)d_in[4];
    const float* Wb    = (const float*)d_in[5];
    const float* bb    = (const float*)d_in[6];
    const float* Ws    = (const float*)d_in[7];
    const float* bs    = (const float*)d_in[8];
    const float* drop1 = (const float*)d_in[9];
    const float* drop2 = (const float*)d_in[10];
    const float* gb    = (const float*)d_in[11];
    const float* gs    = (const float*)d_in[12];
    const int* edge    = (const int*)d_in[13];   // [2, E]
    const int* stem    = (const int*)d_in[14];   // [S]
    float* out = (float*)d_out;

    // workspace (4-byte elems):
    // A[N*64] | B[N*64] | dis[N] | stem01[N] | deg[N] | rowptr[N+1] |
    // hist[N] (NBKT*BBLK=97750 used) | bsum | boff | col[E] | WpT[224*64]
    float* A      = (float*)d_ws;
    float* B      = A + (size_t)N_NODES * 64;
    float* dis    = B + (size_t)N_NODES * 64;
    float* stem01 = dis + N_NODES;
    int*   deg    = (int*)(stem01 + N_NODES);
    int*   rowptr = deg + N_NODES;
    int*   hist   = rowptr + (N_NODES + 1);
    int*   bsum   = hist + N_NODES;
    int*   boff   = bsum + SCAN_BLOCKS;
    int*   col    = boff + SCAN_BLOCKS;
    float* WpT    = (float*)(col + N_EDGES);
    int*   tmp    = (int*)d_out;   // 6.4 MB scratch; out fully overwritten later

    const int* esrc = edge;
    const int* edst = edge + N_EDGES;

    hipMemsetAsync(deg, 0, N_NODES * sizeof(int), stream);
    hipMemsetAsync(stem01, 0, N_NODES * sizeof(float), stream);

    deg_kernel<<<N_EDGES / 256, 256, 0, stream>>>(edst, deg);
    stem_kernel<<<(S_CNT + 255) / 256, 256, 0, stream>>>(stem, stem01);
    dis_kernel<<<SCAN_BLOCKS, 256, 0, stream>>>(deg, dis);
    wpadT_kernel<<<(224 * 64 + 255) / 256, 256, 0, stream>>>(Wb, Ws, WpT);

    // rowptr
    scan1_kernel<<<SCAN_BLOCKS, 256, 0, stream>>>(deg, rowptr, bsum);
    scan2_kernel<<<1, 512, 0, stream>>>(bsum, boff);
    scan3_kernel<<<SCAN_BLOCKS, 256, 0, stream>>>(boff, rowptr);

    // atomic-free binned CSR scatter
    bincnt_kernel<<<BBLK, 256, 0, stream>>>(edst, hist);
    binscan_kernel<<<NBKT, 256, 0, stream>>>(hist, rowptr);
    binscat_kernel<<<BBLK, 256, 0, stream>>>(esrc, edst, hist, tmp);
    bsort_kernel<<<NBKT, 256, 0, stream>>>(tmp, rowptr, col);

    // layer 1: xws1 -> A; h1 -> B
    xw1_kernel<<<N_NODES / 4, 256, 0, stream>>>(x, stem01, dis, W1, A);
    agg_csr_kernel<<<(N_NODES * 64) / 256, 256, 0, stream>>>(A, rowptr, col, dis, b1, drop1, B);

    // layer 2: xws2 -> B (in-place over h1); h2 -> A
    xw2_kernel<<<(N_NODES + 63) / 64, 256, 0, stream>>>(B, dis, W2, B);
    agg_csr_kernel<<<(N_NODES * 64) / 256, 256, 0, stream>>>(B, rowptr, col, dis, b2, drop2, A);

    // fused heads: LDS-W matmul + gumbel softmax -> all 4 output sections
    fh2_kernel<<<dim3(N_NODES / 32, 2), 256, 0, stream>>>(A, WpT, bb, bs, gb, gs, out);
}